// Round 8
// baseline (393.997 us; speedup 1.0000x reference)
//
#include <hip/hip_runtime.h>
#include <math.h>

#define BB 4
#define NN 1024
#define DD 1024
#define HH 16
#define ROWS (BB*NN)   // 4096

typedef __attribute__((ext_vector_type(8))) short bf16x8;
typedef __attribute__((ext_vector_type(4))) float f32x4;
typedef __attribute__((ext_vector_type(4))) unsigned short u16x4;
typedef __attribute__((ext_vector_type(8))) unsigned short u16x8;
typedef unsigned short u16;

__device__ __forceinline__ u16 f2bf(float f) {
    union { float f; unsigned u; } v; v.f = f;
    unsigned r = v.u + 0x7fff + ((v.u >> 16) & 1);
    return (u16)(r >> 16);
}
__device__ __forceinline__ float bf2f(u16 u) {
    union { unsigned u; float f; } v; v.u = ((unsigned)u) << 16; return v.f;
}

// async global->LDS, 16B per lane. LDS dest = wave-uniform base (+lane*16 implicit).
__device__ __forceinline__ void async16(const void* g, void* l) {
    __builtin_amdgcn_global_load_lds(
        (__attribute__((address_space(1))) void*)(uintptr_t)g,
        (__attribute__((address_space(3))) void*)(uintptr_t)l,
        16, 0, 0);
}

// ---------------- block reduce (blockDim = 256) ----------------
__device__ __forceinline__ float block_reduce_sum(float v, float* sm) {
    #pragma unroll
    for (int o = 32; o > 0; o >>= 1) v += __shfl_down(v, o);
    int lane = threadIdx.x & 63, wid = threadIdx.x >> 6;
    if (lane == 0) sm[wid] = v;
    __syncthreads();
    if (wid == 0) {
        v = (lane < (int)(blockDim.x >> 6)) ? sm[lane] : 0.f;
        #pragma unroll
        for (int o = 2; o > 0; o >>= 1) v += __shfl_down(v, o);
        if (lane == 0) sm[0] = v;
    }
    __syncthreads();
    float r = sm[0];
    __syncthreads();
    return r;
}

// 3 sums in one barrier round
__device__ __forceinline__ void block_reduce3(float& a, float& b, float& c, float* sm) {
    #pragma unroll
    for (int o = 32; o > 0; o >>= 1) {
        a += __shfl_down(a, o); b += __shfl_down(b, o); c += __shfl_down(c, o);
    }
    int lane = threadIdx.x & 63, wid = threadIdx.x >> 6;
    if (lane == 0) { sm[wid] = a; sm[8 + wid] = b; sm[16 + wid] = c; }
    __syncthreads();
    int nw = (int)(blockDim.x >> 6);
    if (wid == 0) {
        float va = (lane < nw) ? sm[lane] : 0.f;
        float vb = (lane < nw) ? sm[8 + lane] : 0.f;
        float vc = (lane < nw) ? sm[16 + lane] : 0.f;
        #pragma unroll
        for (int o = 2; o > 0; o >>= 1) {
            va += __shfl_down(va, o); vb += __shfl_down(vb, o); vc += __shfl_down(vc, o);
        }
        if (lane == 0) { sm[0] = va; sm[8] = vb; sm[16] = vc; }
    }
    __syncthreads();
    a = sm[0]; b = sm[8]; c = sm[16];
    __syncthreads();
}

// ---------------- fused: weight transpose+convert (6 weights) AND layernorm1 ----------------
// Wpj is transposed with a +1 row shift (WpjT'[n][j] = Wpj[j+1][n], j=4095 zeroed):
// the gelu-fused FFN stores hg without a time column; the time term is added in
// the Wpj GEMM epilogue from tsum + Wpj row 0 (read from the original input).
__global__ __launch_bounds__(256) void k_pre(
        const float* __restrict__ Wq_, const float* __restrict__ Wk_,
        const float* __restrict__ Wv_, const float* __restrict__ Wo_,
        const float* __restrict__ Wfc_, const float* __restrict__ Wpj_,
        u16* __restrict__ WqkvT, u16* __restrict__ WoT,
        u16* __restrict__ WfcT, u16* __restrict__ WpjT,
        const float* __restrict__ x, const float* __restrict__ g1,
        const float* __restrict__ be1, u16* __restrict__ lnout) {
    __shared__ float t[32][33];
    int bid = blockIdx.x;
    if (bid < 12352) {
        const float* W; u16* out; int K, N, Kpad, Npad, gx, shift = 0;
        if (bid < 1024)      { W = Wq_;  out = WqkvT;            K = 1024; N = 1024; Kpad = 1024; Npad = 1024; gx = 32; }
        else if (bid < 2048) { W = Wk_;  out = WqkvT + 1048576;  K = 1024; N = 1024; Kpad = 1024; Npad = 1024; gx = 32; bid -= 1024; }
        else if (bid < 3072) { W = Wv_;  out = WqkvT + 2097152;  K = 1024; N = 1024; Kpad = 1024; Npad = 1024; gx = 32; bid -= 2048; }
        else if (bid < 4160) { W = Wo_;  out = WoT;              K = 1040; N = 1023; Kpad = 1088; Npad = 1024; gx = 34; bid -= 3072; }
        else if (bid < 8256) { W = Wfc_; out = WfcT;             K = 1024; N = 4095; Kpad = 1024; Npad = 4096; gx = 32; bid -= 4160; }
        else                 { W = Wpj_; out = WpjT;             K = 4095; N = 1023; Kpad = 4096; Npad = 1024; gx = 128; shift = 1; bid -= 8256; }
        int k0 = (bid % gx) * 32, n0 = (bid / gx) * 32;
        int tx = threadIdx.x & 31, ty = threadIdx.x >> 5;
        #pragma unroll
        for (int i = 0; i < 32; i += 8) {
            int k = k0 + ty + i, n = n0 + tx;
            t[ty + i][tx] = (k < K && n < N) ? W[(size_t)(k + shift) * N + n] : 0.f;
        }
        __syncthreads();
        #pragma unroll
        for (int i = 0; i < 32; i += 8) {
            int n = n0 + ty + i, k = k0 + tx;
            if (n < Npad && k < Kpad) out[(size_t)n * Kpad + k] = f2bf(t[tx][ty + i]);
        }
    } else {
        float* sm = &t[0][0];
        int row = bid - 12352, tid = threadIdx.x;
        const float4* xr4 = (const float4*)(x + (size_t)row * DD);
        float4 xv = xr4[tid];
        float s = 0.f, ss = 0.f, dummy = 0.f;
        #pragma unroll
        for (int e = 0; e < 4; ++e) {
            if (tid | e) {
                float v = ((const float*)&xv)[e];
                s += v; ss += v * v;
            }
        }
        block_reduce3(s, ss, dummy, sm);
        float mu = s * (1.f / 1023.f);
        float var = ss * (1.f / 1023.f) - mu * mu;
        float rstd = rsqrtf(var + 1e-5f);
        float vo[4]; float s2 = 0.f;
        #pragma unroll
        for (int e = 0; e < 4; ++e) {
            int c = 4 * tid + e;
            if (c > 0) {
                float v = (((const float*)&xv)[e] - mu) * rstd * g1[c - 1] + be1[c - 1];
                vo[e] = v; s2 += v * v;
            } else vo[e] = 0.f;
        }
        s2 = block_reduce_sum(s2, sm);
        u16x4 lo;
        #pragma unroll
        for (int e = 0; e < 4; ++e) lo[e] = f2bf(vo[e]);
        if (tid == 0) lo[0] = f2bf(sqrtf(s2 + 1.f));
        ((u16x4*)(lnout + (size_t)row * DD))[tid] = lo;
    }
}

// ---------------- bf16 MFMA GEMM: single-barrier double-buffered K-loop ----------------
// u16 output: LDS-staged epilogue (coalesced u16x8 stores, conflict-free stride-128).
// float: direct stores; optional time-term fixup (+ sqrt(tsum[row]+1)*w0[col], z==0 only).
__device__ __forceinline__ void cstore(float* p, float v) { *p = v; }
__device__ __forceinline__ void cstore(u16* p, float v) { *p = f2bf(v); }

template <typename OT>
__global__ __launch_bounds__(256) void k_gemm_mfma(
        const u16* __restrict__ A, const u16* __restrict__ BT,
        const float* __restrict__ bias, int nbias,
        OT* __restrict__ C0, OT* __restrict__ C1,
        int ldc, int ldab, int ksplit, int K, int swz,
        const float* __restrict__ tsum_, const float* __restrict__ w0_) {
    __shared__ __align__(16) u16 smem[32768];   // As | Bs during K-loop; C-staging after
    int z = blockIdx.z;
    int kbeg = z ? ksplit : 0;
    int kend = z ? K : ksplit;
    OT* C = z ? C1 : C0;
    const float* bs = z ? nullptr : bias;

    int bx = blockIdx.x, by = blockIdx.y;
    if (swz) {
        // hw XCD = (bx + nx*by) % 8. Remap so XCD c owns m-panels [c*ny/8, ...).
        int nx = gridDim.x, ny = gridDim.y;
        int flat = bx + nx * by;
        int c = flat & 7, i = flat >> 3;
        int hi = i / nx;
        by = c * (ny >> 3) + hi;
        bx = i - hi * nx;
    }

    int tid = threadIdx.x;
    int wave = tid >> 6, lane = tid & 63;
    int quad = lane >> 4, m16 = lane & 15;
    int n0 = bx * 128, m0 = by * 128;
    int wm = (wave & 1) * 64, wn = (wave >> 1) * 64;

    f32x4 acc[4][4];
    #pragma unroll
    for (int t = 0; t < 4; ++t)
        #pragma unroll
        for (int u = 0; u < 4; ++u) acc[t][u] = (f32x4){0.f, 0.f, 0.f, 0.f};

    int r8 = lane >> 3;
    int cc = (lane & 7) ^ r8;               // XOR chunk swizzle (bank-conflict-free, measured 0)
    int srow = wave * 32 + r8;
    const u16* ag = A  + (size_t)(m0 + srow) * ldab + cc * 8;
    const u16* bg = BT + (size_t)(n0 + srow) * ldab + cc * 8;

    auto stage = [&](int k0, int s) {
        #pragma unroll
        for (int j = 0; j < 4; ++j) {
            async16(ag + (size_t)(j * 8) * ldab + k0, &smem[s * 8192 + (wave * 32 + j * 8) * 64]);
            async16(bg + (size_t)(j * 8) * ldab + k0, &smem[16384 + s * 8192 + (wave * 32 + j * 8) * 64]);
        }
    };

    int niter = (kend - kbeg) >> 6;
    stage(kbeg, 0);
    for (int it = 0; it < niter; ++it) {
        int cur = it & 1;
        __syncthreads();                    // drains stage(it) + prior iter's LDS reads
        if (it + 1 < niter) stage(kbeg + (it + 1) * 64, cur ^ 1);
        #pragma unroll
        for (int kk = 0; kk < 2; ++kk) {
            bf16x8 af[4], bfr[4];
            #pragma unroll
            for (int t = 0; t < 4; ++t) {
                int slot = (kk * 4 + quad) ^ (m16 & 7);
                af[t] = *(const bf16x8*)&smem[cur * 8192 + (wm + t * 16 + m16) * 64 + slot * 8];
            }
            #pragma unroll
            for (int u = 0; u < 4; ++u) {
                int slot = (kk * 4 + quad) ^ (m16 & 7);
                bfr[u] = *(const bf16x8*)&smem[16384 + cur * 8192 + (wn + u * 16 + m16) * 64 + slot * 8];
            }
            #pragma unroll
            for (int t = 0; t < 4; ++t)
                #pragma unroll
                for (int u = 0; u < 4; ++u)
                    acc[t][u] = __builtin_amdgcn_mfma_f32_16x16x32_bf16(af[t], bfr[u], acc[t][u], 0, 0, 0);
        }
    }
    if constexpr (sizeof(OT) == 2) {
        // bf16 out: stage 128x128 u16 tile in LDS, then coalesced row copies.
        __syncthreads();
        #pragma unroll
        for (int u = 0; u < 4; ++u) {
            int col = n0 + wn + u * 16 + m16;
            float bv = (bs != nullptr && col < nbias) ? bs[col] : 0.f;
            #pragma unroll
            for (int t = 0; t < 4; ++t) {
                #pragma unroll
                for (int r = 0; r < 4; ++r)
                    smem[(wm + t * 16 + quad * 4 + r) * 128 + wn + u * 16 + m16] = f2bf(acc[t][u][r] + bv);
            }
        }
        __syncthreads();
        u16* Cg = (u16*)C;
        for (int i = tid; i < 2048; i += 256) {
            int rr = i >> 4, ch = i & 15;
            ((u16x8*)(Cg + (size_t)(m0 + rr) * ldc + n0))[ch] = ((const u16x8*)(smem + rr * 128))[ch];
        }
    } else {
        float trow[4][4];
        #pragma unroll
        for (int t = 0; t < 4; ++t)
            #pragma unroll
            for (int r = 0; r < 4; ++r) trow[t][r] = 0.f;
        bool fix = (tsum_ != nullptr && bs != nullptr);
        if (fix) {
            #pragma unroll
            for (int t = 0; t < 4; ++t)
                #pragma unroll
                for (int r = 0; r < 4; ++r)
                    trow[t][r] = sqrtf(tsum_[m0 + wm + t * 16 + quad * 4 + r] + 1.f);
        }
        #pragma unroll
        for (int u = 0; u < 4; ++u) {
            int col = n0 + wn + u * 16 + m16;
            if (col < nbias) {
                float bv = (bs != nullptr) ? bs[col] : 0.f;
                float w0c = fix ? w0_[col] : 0.f;
                #pragma unroll
                for (int t = 0; t < 4; ++t) {
                    #pragma unroll
                    for (int r = 0; r < 4; ++r) {
                        int row = m0 + wm + t * 16 + quad * 4 + r;
                        cstore(C + (size_t)row * ldc + col, acc[t][u][r] + bv + trow[t][r] * w0c);
                    }
                }
            }
        }
    }
}

// ---------------- fused Wfc GEMM + bias + exact gelu + per-row sumsq (atomic) ----------------
// Writes hg[row][j] = gelu(fc_j) bf16 (col 4095 = 0); atomicAdds per-row sum(gl^2)
// into tsum[row] (zeroed by k_lresnet_ln). Time term applied later in Wpj GEMM.
__global__ __launch_bounds__(256) void k_gemm_gelu(
        const u16* __restrict__ A, const u16* __restrict__ BT,
        const float* __restrict__ bias,
        u16* __restrict__ C, float* __restrict__ tsum) {
    __shared__ __align__(16) u16 smem[32768];
    int tid = threadIdx.x;
    int wave = tid >> 6, lane = tid & 63;
    int quad = lane >> 4, m16 = lane & 15;
    int n0 = blockIdx.x * 128, m0 = blockIdx.y * 128;
    int wm = (wave & 1) * 64, wn = (wave >> 1) * 64;

    f32x4 acc[4][4];
    #pragma unroll
    for (int t = 0; t < 4; ++t)
        #pragma unroll
        for (int u = 0; u < 4; ++u) acc[t][u] = (f32x4){0.f, 0.f, 0.f, 0.f};

    int r8 = lane >> 3;
    int cc = (lane & 7) ^ r8;
    int srow = wave * 32 + r8;
    const u16* ag = A  + (size_t)(m0 + srow) * 1024 + cc * 8;
    const u16* bg = BT + (size_t)(n0 + srow) * 1024 + cc * 8;

    auto stage = [&](int k0, int s) {
        #pragma unroll
        for (int j = 0; j < 4; ++j) {
            async16(ag + (size_t)(j * 8) * 1024 + k0, &smem[s * 8192 + (wave * 32 + j * 8) * 64]);
            async16(bg + (size_t)(j * 8) * 1024 + k0, &smem[16384 + s * 8192 + (wave * 32 + j * 8) * 64]);
        }
    };

    stage(0, 0);
    for (int it = 0; it < 16; ++it) {
        int cur = it & 1;
        __syncthreads();
        if (it + 1 < 16) stage((it + 1) * 64, cur ^ 1);
        #pragma unroll
        for (int kk = 0; kk < 2; ++kk) {
            bf16x8 af[4], bfr[4];
            #pragma unroll
            for (int t = 0; t < 4; ++t) {
                int slot = (kk * 4 + quad) ^ (m16 & 7);
                af[t] = *(const bf16x8*)&smem[cur * 8192 + (wm + t * 16 + m16) * 64 + slot * 8];
            }
            #pragma unroll
            for (int u = 0; u < 4; ++u) {
                int slot = (kk * 4 + quad) ^ (m16 & 7);
                bfr[u] = *(const bf16x8*)&smem[16384 + cur * 8192 + (wn + u * 16 + m16) * 64 + slot * 8];
            }
            #pragma unroll
            for (int t = 0; t < 4; ++t)
                #pragma unroll
                for (int u = 0; u < 4; ++u)
                    acc[t][u] = __builtin_amdgcn_mfma_f32_16x16x32_bf16(af[t], bfr[u], acc[t][u], 0, 0, 0);
        }
    }

    // epilogue: gelu + stage + per-row partial sumsq
    __syncthreads();
    float rs[4][4];
    #pragma unroll
    for (int t = 0; t < 4; ++t)
        #pragma unroll
        for (int r = 0; r < 4; ++r) rs[t][r] = 0.f;
    #pragma unroll
    for (int u = 0; u < 4; ++u) {
        int col = n0 + wn + u * 16 + m16;
        bool valid = col < 4095;
        float bv = valid ? bias[col] : 0.f;
        #pragma unroll
        for (int t = 0; t < 4; ++t) {
            #pragma unroll
            for (int r = 0; r < 4; ++r) {
                float v = acc[t][u][r] + bv;
                float gl = valid ? 0.5f * v * (1.f + erff(v * 0.70710678f)) : 0.f;
                smem[(wm + t * 16 + quad * 4 + r) * 128 + wn + u * 16 + m16] = f2bf(gl);
                rs[t][r] += gl * gl;
            }
        }
    }
    #pragma unroll
    for (int t = 0; t < 4; ++t) {
        #pragma unroll
        for (int r = 0; r < 4; ++r) {
            float s = rs[t][r];
            s += __shfl_xor(s, 1); s += __shfl_xor(s, 2);
            s += __shfl_xor(s, 4); s += __shfl_xor(s, 8);
            if (m16 == 0) atomicAdd(&tsum[m0 + wm + t * 16 + quad * 4 + r], s);
        }
    }
    __syncthreads();
    for (int i = tid; i < 2048; i += 256) {
        int rr = i >> 4, ch = i & 15;
        ((u16x8*)(C + (size_t)(m0 + rr) * 4096 + n0))[ch] = ((const u16x8*)(smem + rr * 128))[ch];
    }
}

// ---------------- fused QKV GEMM + bias + lift + head layouts (direct-store epilogue) ----------------
__global__ __launch_bounds__(256) void k_gemm_qkv(
        const u16* __restrict__ A, const u16* __restrict__ BT,
        const float* __restrict__ bq, const float* __restrict__ bk,
        const float* __restrict__ bv,
        u16* __restrict__ Qp, u16* __restrict__ Kp, u16* __restrict__ V2) {
    __shared__ __align__(16) u16 smem[32768];
    int tid = threadIdx.x;
    int wave = tid >> 6, lane = tid & 63;
    int quad = lane >> 4, m16 = lane & 15;
    int n0 = blockIdx.x * 128, m0 = blockIdx.y * 128;
    int wm = (wave & 1) * 64, wn = (wave >> 1) * 64;

    f32x4 acc[4][4];
    #pragma unroll
    for (int t = 0; t < 4; ++t)
        #pragma unroll
        for (int u = 0; u < 4; ++u) acc[t][u] = (f32x4){0.f, 0.f, 0.f, 0.f};

    int r8 = lane >> 3;
    int cc = (lane & 7) ^ r8;
    int srow = wave * 32 + r8;
    const u16* ag = A  + (size_t)(m0 + srow) * 1024 + cc * 8;
    const u16* bg = BT + (size_t)(n0 + srow) * 1024 + cc * 8;

    auto stage = [&](int k0, int s) {
        #pragma unroll
        for (int j = 0; j < 4; ++j) {
            async16(ag + (size_t)(j * 8) * 1024 + k0, &smem[s * 8192 + (wave * 32 + j * 8) * 64]);
            async16(bg + (size_t)(j * 8) * 1024 + k0, &smem[16384 + s * 8192 + (wave * 32 + j * 8) * 64]);
        }
    };

    stage(0, 0);
    for (int it = 0; it < 16; ++it) {
        int cur = it & 1;
        __syncthreads();
        if (it + 1 < 16) stage((it + 1) * 64, cur ^ 1);
        #pragma unroll
        for (int kk = 0; kk < 2; ++kk) {
            bf16x8 af[4], bfr[4];
            #pragma unroll
            for (int t = 0; t < 4; ++t) {
                int slot = (kk * 4 + quad) ^ (m16 & 7);
                af[t] = *(const bf16x8*)&smem[cur * 8192 + (wm + t * 16 + m16) * 64 + slot * 8];
            }
            #pragma unroll
            for (int u = 0; u < 4; ++u) {
                int slot = (kk * 4 + quad) ^ (m16 & 7);
                bfr[u] = *(const bf16x8*)&smem[16384 + cur * 8192 + (wn + u * 16 + m16) * 64 + slot * 8];
            }
            #pragma unroll
            for (int t = 0; t < 4; ++t)
                #pragma unroll
                for (int u = 0; u < 4; ++u)
                    acc[t][u] = __builtin_amdgcn_mfma_f32_16x16x32_bf16(af[t], bfr[u], acc[t][u], 0, 0, 0);
        }
    }

    // ---- epilogue: build heads in-place (direct stores; measured faster than LDS staging) ----
    int sec = n0 >> 10;                       // 0=Q 1=K 2=V (uniform per block)
    int h = ((n0 & 1023) + wn) >> 6;          // this wave's head
    int b = m0 >> 10;                         // batch (uniform per block)
    int b16h = b * 16 + h;
    const float* bias = (sec == 0) ? bq : (sec == 1) ? bk : bv;
    float bvu[4];
    #pragma unroll
    for (int u = 0; u < 4; ++u) bvu[u] = bias[h * 64 + u * 16 + m16];

    if (sec < 2) {
        const int strd = (sec == 0) ? 96 : 104;
        u16* P = (sec == 0) ? Qp : Kp;
        const float tsign = (sec == 0) ? -1.f : 1.f;
        #pragma unroll
        for (int t = 0; t < 4; ++t) {
            #pragma unroll
            for (int r = 0; r < 4; ++r) {
                int n = (m0 + wm + t * 16 + quad * 4 + r) & 1023;
                u16* drow = P + ((size_t)b16h * 1024 + n) * strd;
                float vv[4]; float ss = 0.f;
                #pragma unroll
                for (int u = 0; u < 4; ++u) { vv[u] = acc[t][u][r] + bvu[u]; ss += vv[u] * vv[u]; }
                ss += __shfl_xor(ss, 1); ss += __shfl_xor(ss, 2);
                ss += __shfl_xor(ss, 4); ss += __shfl_xor(ss, 8);
                #pragma unroll
                for (int u = 0; u < 4; ++u) drow[1 + u * 16 + m16] = f2bf(vv[u]);
                if (m16 == 0) drow[0] = f2bf(tsign * sqrtf(ss + 1.f));
                drow[65 + m16] = 0;
                if (m16 < 15) drow[81 + m16] = 0;
            }
        }
    } else {
        int tile = ((m0 & 1023) + wm) >> 6;   // this wave's 64-token tile
        size_t tbase = ((size_t)b16h * 16 + tile) * 6144;
        #pragma unroll
        for (int t = 0; t < 4; ++t) {
            int tok0 = t * 16 + quad * 4;
            u16x4 tc;
            u16x4 pk[4];
            #pragma unroll
            for (int r = 0; r < 4; ++r) {
                float vv[4]; float ss = 0.f;
                #pragma unroll
                for (int u = 0; u < 4; ++u) { vv[u] = acc[t][u][r] + bvu[u]; ss += vv[u] * vv[u]; }
                ss += __shfl_xor(ss, 1); ss += __shfl_xor(ss, 2);
                ss += __shfl_xor(ss, 4); ss += __shfl_xor(ss, 8);
                tc[r] = f2bf(sqrtf(ss + 1.f));
                #pragma unroll
                for (int u = 0; u < 4; ++u) pk[u][r] = f2bf(vv[u]);
            }
            #pragma unroll
            for (int u = 0; u < 4; ++u) {
                int d = u * 16 + m16;
                *(u16x4*)&V2[tbase + (size_t)(1 + d) * 72 + tok0] = pk[u];
            }
            if (m16 == 0) *(u16x4*)&V2[tbase + tok0] = tc;   // time row (d=0)
        }
        // zero pad rows d=65..79 (read by PV MFMA, must be 0)
        for (int i = lane; i < 240; i += 64) {
            int rr = 65 + (i >> 4), sg = (i & 15) << 2;
            *(u16x4*)&V2[tbase + (size_t)rr * 72 + sg] = (u16x4){0, 0, 0, 0};
        }
    }
}

// ---------------- MFMA flash attention v5: 8-wave blocks for 2x occupancy ----------------
#define AKS 104
#define AVS 72
#define APS 88
#define KTILE_U16 (64 * AKS)   // 6656
#define VTILE_U16 6144
#define EXPC 0.36067376f       // 0.25 * log2(e)
__global__ __launch_bounds__(512) void k_attn_mfma(
        const u16* __restrict__ Qp, const u16* __restrict__ Kp,
        const u16* __restrict__ V2, u16* __restrict__ cat) {
    __shared__ __align__(16) u16 Klds[2][KTILE_U16];
    __shared__ __align__(16) u16 Vlds[2][VTILE_U16];
    __shared__ __align__(16) u16 Plds[8][16 * APS];
    int tid = threadIdx.x;
    int wave = tid >> 6, lane = tid & 63;
    int quad = lane >> 4, m = lane & 15;
    int wq = wave & 3, g = wave >> 2;
    int bid = blockIdx.x;
    int bh = ((bid & 7) << 3) | (bid >> 6);
    int qt = (bid >> 3) & 7;

    const u16* kg = Kp + (size_t)bh * 16 * KTILE_U16;
    const u16* vg = V2 + (size_t)bh * 16 * VTILE_U16;

    bf16x8 aq[3];
    {
        const u16* qptr = Qp + ((size_t)bh * 1024 + qt * 128 + g * 64 + wq * 16 + m) * 96;
        aq[0] = *(const bf16x8*)(qptr + quad * 8);
        aq[1] = *(const bf16x8*)(qptr + 32 + quad * 8);
        aq[2] = *(const bf16x8*)(qptr + 64 + quad * 8);
    }

    f32x4 O[5];
    #pragma unroll
    for (int i = 0; i < 5; ++i) O[i] = (f32x4){0.f, 0.f, 0.f, 0.f};

    auto stage = [&](int kt, int s) {
        const u16* kt_p = kg + kt * KTILE_U16 + lane * 8;
        const u16* vt_p = vg + kt * VTILE_U16 + lane * 8;
        for (int i = wave; i < 25; i += 8) {
            if (i < 13) async16(kt_p + i * 512, &Klds[s][i * 512]);
            else        async16(vt_p + (i - 13) * 512, &Vlds[s][(i - 13) * 512]);
        }
    };

    stage(0, 0);
    for (int kt = 0; kt < 16; ++kt) {
        int cur = kt & 1;
        __syncthreads();
        if (kt < 15) stage(kt + 1, cur ^ 1);
        u16* pw = &Plds[wave][0];
        #pragma unroll
        for (int nt = 0; nt < 4; ++nt) {
            f32x4 acc = (f32x4){0.f, 0.f, 0.f, 0.f};
            const u16* kr = &Klds[cur][(nt * 16 + m) * AKS + quad * 8];
            acc = __builtin_amdgcn_mfma_f32_16x16x32_bf16(*(const bf16x8*)(kr),      aq[0], acc, 0, 0, 0);
            acc = __builtin_amdgcn_mfma_f32_16x16x32_bf16(*(const bf16x8*)(kr + 32), aq[1], acc, 0, 0, 0);
            acc = __builtin_amdgcn_mfma_f32_16x16x32_bf16(*(const bf16x8*)(kr + 64), aq[2], acc, 0, 0, 0);
            unsigned pk0, pk1;
            {
                union { float f; unsigned u; } a0, a1, a2, a3;
                a0.f = __builtin_amdgcn_exp2f(fmaf(acc[0], EXPC, EXPC));
                a1.f = __builtin_amdgcn_exp2f(fmaf(acc[1], EXPC, EXPC));
                a2.f = __builtin_amdgcn_exp2f(fmaf(acc[2], EXPC, EXPC));
                a3.f = __builtin_amdgcn_exp2f(fmaf(acc[3], EXPC, EXPC));
                pk0 = ((a0.u + 0x8000u) >> 16) | (((a1.u + 0x8000u) >> 16) << 16);
                pk1 = ((a2.u + 0x8000u) >> 16) | (((a3.u + 0x8000u) >> 16) << 16);
            }
            uint2 pk; pk.x = pk0; pk.y = pk1;
            *(uint2*)&pw[m * APS + nt * 16 + quad * 4] = pk;
        }
        #pragma unroll
        for (int kc = 0; kc < 2; ++kc) {
            bf16x8 ap = *(const bf16x8*)&Plds[wave][m * APS + kc * 32 + quad * 8];
            #pragma unroll
            for (int vt = 0; vt < 5; ++vt) {
                bf16x8 bv = *(const bf16x8*)&Vlds[cur][(vt * 16 + m) * AVS + kc * 32 + quad * 8];
                O[vt] = __builtin_amdgcn_mfma_f32_16x16x32_bf16(ap, bv, O[vt], 0, 0, 0);
            }
        }
    }
    int b = bh >> 4, h = bh & 15;
    #pragma unroll
    for (int r = 0; r < 4; ++r) {
        float part = 0.f;
        #pragma unroll
        for (int vt = 0; vt < 5; ++vt) {
            int c = vt * 16 + m;
            float o = O[vt][r];
            part += (c == 0) ? o * o : -o * o;
        }
        part += __shfl_xor(part, 1);
        part += __shfl_xor(part, 2);
        part += __shfl_xor(part, 4);
        part += __shfl_xor(part, 8);
        float rden = rsqrtf(fmaxf(part, 1e-8f));
        int n = qt * 128 + g * 64 + wq * 16 + quad * 4 + r;
        u16* crow = cat + (size_t)(b * 1024 + n) * 1088 + h * 65;
        #pragma unroll
        for (int vt = 0; vt < 5; ++vt) {
            int c = vt * 16 + m;
            if (c < 65) crow[c] = f2bf(O[vt][r] * rden);
        }
    }
    if (h == 15) {
        for (int i = tid; i < 128 * 48; i += 512) {
            int rr = i / 48, c = i - rr * 48;
            int n = qt * 128 + rr;
            cat[(size_t)(b * 1024 + n) * 1088 + 1040 + c] = 0;
        }
    }
}

// ---------------- fused lift(y0+y1) + lresnet + layernorm2 (vectorized, aligned) ----------------
// Also zeroes tsum[row] for the downstream gelu-fused FFN.
__global__ __launch_bounds__(256) void k_lresnet_ln(
        const float* __restrict__ x, const float* __restrict__ y0,
        const float* __restrict__ y1, const float* __restrict__ wscale,
        const float* __restrict__ g2, const float* __restrict__ be2,
        float* __restrict__ x1, u16* __restrict__ lnout,
        float* __restrict__ tsum) {
    __shared__ float sm[24];
    __shared__ float edge[256];
    int row = blockIdx.x, tid = threadIdx.x;
    if (tid == 0) tsum[row] = 0.f;
    float w = *wscale;
    float4 xv = ((const float4*)(x  + (size_t)row * DD))[tid];
    float4 av = ((const float4*)(y0 + (size_t)row * 1024))[tid];
    float4 bv = ((const float4*)(y1 + (size_t)row * 1024))[tid];
    float yv[4];
    #pragma unroll
    for (int e = 0; e < 4; ++e) yv[e] = ((const float*)&av)[e] + ((const float*)&bv)[e];
    edge[tid] = yv[3];
    float sy = 0.f;
    #pragma unroll
    for (int e = 0; e < 4; ++e) if (4 * tid + e < 1023) sy += yv[e] * yv[e];
    __syncthreads();
    float yprev = tid ? edge[tid - 1] : 0.f;
    float zv[4];
    float sz = 0.f, szs = 0.f;
    #pragma unroll
    for (int e = 0; e < 4; ++e) {
        float yc = (e == 0) ? yprev : yv[e - 1];   // y[c-1] for col c=4tid+e
        float z = ((const float*)&xv)[e] + w * yc;
        zv[e] = z;
        if (tid | e) { sz += z * z; szs += z; }
    }
    block_reduce3(sy, sz, szs, sm);
    float x0 = x[(size_t)row * DD];
    float z0 = x0 + w * sqrtf(sy + 1.f);
    float q = z0 * z0 - sz;
    float rden = rsqrtf(fmaxf(q, 1e-8f));
    float mu = rden * szs * (1.f / 1023.f);
    float ex2 = rden * rden * sz * (1.f / 1023.f);
    float rstd = rsqrtf(ex2 - mu * mu + 1e-5f);
    float4 xo; float vo[4]; float s2 = 0.f;
    #pragma unroll
    for (int e = 0; e < 4; ++e) {
        int c = 4 * tid + e;
        float xn = zv[e] * rden;
        ((float*)&xo)[e] = xn;
        if (c > 0) {
            float v = (xn - mu) * rstd * g2[c - 1] + be2[c - 1];
            vo[e] = v; s2 += v * v;
        } else vo[e] = 0.f;
    }
    if (tid == 0) ((float*)&xo)[0] = z0 * rden;
    ((float4*)(x1 + (size_t)row * DD))[tid] = xo;
    s2 = block_reduce_sum(s2, sm);
    u16x4 lo;
    #pragma unroll
    for (int e = 0; e < 4; ++e) lo[e] = f2bf(vo[e]);
    if (tid == 0) lo[0] = f2bf(sqrtf(s2 + 1.f));
    ((u16x4*)(lnout + (size_t)row * DD))[tid] = lo;
}

// ---------------- final lresnet (fp32 out, vectorized, aligned) ----------------
__global__ __launch_bounds__(256) void k_lresnet(
        const float* __restrict__ x, const float* __restrict__ y0,
        const float* __restrict__ y1, const float* __restrict__ wscale,
        float* __restrict__ out) {
    __shared__ float sm[24];
    __shared__ float edge[256];
    int row = blockIdx.x, tid = threadIdx.x;
    float w = *wscale;
    float4 xv = ((const float4*)(x  + (size_t)row * DD))[tid];
    float4 av = ((const float4*)(y0 + (size_t)row * 1024))[tid];
    float4 bv = ((const float4*)(y1 + (size_t)row * 1024))[tid];
    float yv[4];
    #pragma unroll
    for (int e = 0; e < 4; ++e) yv[e] = ((const float*)&av)[e] + ((const float*)&bv)[e];
    edge[tid] = yv[3];
    float sy = 0.f;
    #pragma unroll
    for (int e = 0; e < 4; ++e) if (4 * tid + e < 1023) sy += yv[e] * yv[e];
    __syncthreads();
    float yprev = tid ? edge[tid - 1] : 0.f;
    float zv[4];
    float sz = 0.f, dummy = 0.f;
    #pragma unroll
    for (int e = 0; e < 4; ++e) {
        float yc = (e == 0) ? yprev : yv[e - 1];
        float z = ((const float*)&xv)[e] + w * yc;
        zv[e] = z;
        if (tid | e) sz += z * z;
    }
    block_reduce3(sy, sz, dummy, sm);
    float x0 = x[(size_t)row * DD];
    float z0 = x0 + w * sqrtf(sy + 1.f);
    float q = z0 * z0 - sz;
    float rden = rsqrtf(fmaxf(q, 1e-8f));
    float4 o;
    #pragma unroll
    for (int e = 0; e < 4; ++e) ((float*)&o)[e] = zv[e] * rden;
    if (tid == 0) ((float*)&o)[0] = z0 * rden;
    ((float4*)(out + (size_t)row * DD))[tid] = o;
}

// ---------------- launch ----------------
extern "C" void kernel_launch(void* const* d_in, const int* in_sizes, int n_in,
                              void* d_out, int out_size, void* d_ws, size_t ws_size,
                              hipStream_t stream) {
    const float* x   = (const float*)d_in[0];
    const float* g1  = (const float*)d_in[1];
    const float* b1  = (const float*)d_in[2];
    const float* Wq  = (const float*)d_in[3];
    const float* bq  = (const float*)d_in[4];
    const float* Wk  = (const float*)d_in[5];
    const float* bk  = (const float*)d_in[6];
    const float* Wv  = (const float*)d_in[7];
    const float* bv  = (const float*)d_in[8];
    const float* Wo  = (const float*)d_in[9];
    const float* bo  = (const float*)d_in[10];
    const float* g2  = (const float*)d_in[11];
    const float* b2  = (const float*)d_in[12];
    const float* Wfc = (const float*)d_in[13];
    const float* bfc = (const float*)d_in[14];
    const float* Wpj = (const float*)d_in[15];
    const float* bpj = (const float*)d_in[16];
    const float* w1  = (const float*)d_in[17];
    const float* w2  = (const float*)d_in[18];
    float* out = (float*)d_out;

    char* W = (char*)d_ws;
    // byte offsets; peak 117,571,584 B (unchanged)
    u16* lx_bf  = (u16*)(W + 0);            // 8 MB (ln1, later ln2)
    u16* WqkvT  = (u16*)(W + 8388608);      // [3072][1024]; dead after step 2 -> tsum overlay
    u16* WoT    = (u16*)(W + 14680064);     // [1024][1088]
    u16* WfcT   = (u16*)(W + 16908288);     // [4096][1024]
    u16* WpjT   = (u16*)(W + 25296896);     // [1024][4096], row-shifted (+1)
    u16* Qp     = (u16*)(W + 58851328);     // 64x1024x96
    u16* Kp     = (u16*)(W + 71434240);     // 64x1024x104
    u16* V2     = (u16*)(W + 85065728);     // 64x16x6144
    u16* cat_bf = (u16*)(W + 97648640);     // 4096x1088
    float* ax0  = (float*)(W + 33685504);   // overlay (dead region); unshifted rows
    float* ax1  = (float*)(W + 50462720);   // overlay (dead region); unshifted rows
    float* x1   = (float*)(W + 67239936);   // overlay Qp-tail/Kp (dead)
    u16* hg_bf  = (u16*)(W + 33685504);     // 32MB, overlay ax0/ax1 (dead); gelu values, col4095=0
    float* h2a  = (float*)(W + 84017152);   // overlay Kp-tail/V2/cat (dead)
    float* h2b  = (float*)(W + 100794368);
    float* tsum = (float*)(W + 8388608);    // 16 KB, overlay dead WqkvT; zeroed in step 5

    dim3 blk(256);

    // 1) weight conversion + layernorm1 (fused; Wpj transposed with +1 row shift)
    k_pre<<<16448, blk, 0, stream>>>(Wq, Wk, Wv, Wo, Wfc, Wpj,
                                     WqkvT, WoT, WfcT, WpjT,
                                     x, g1, b1, lx_bf);

    // 2) fused QKV GEMM + bias + lift + head layouts (direct-store epilogue)
    k_gemm_qkv<<<dim3(24, 32, 1), blk, 0, stream>>>(
        lx_bf, WqkvT, bq, bk, bv, Qp, Kp, V2);

    // 3) MFMA flash attention v5 (8-wave blocks, XCD-swizzled 1D grid)
    k_attn_mfma<<<512, dim3(512), 0, stream>>>(Qp, Kp, V2, cat_bf);

    // 4) ax = cat @ Wo + bo, split-K (576+512); XCD m-panel swizzle
    k_gemm_mfma<float><<<dim3(8, 32, 2), blk, 0, stream>>>(
        cat_bf, WoT, bo, 1023, ax0, ax1, 1024, 1088, 576, 1088, 1, nullptr, nullptr);

    // 5) x1 = lresnet(x, lift(ax0+ax1), w1); ln2 -> lx_bf; zero tsum
    k_lresnet_ln<<<ROWS, blk, 0, stream>>>(x, ax0, ax1, w1, g2, b2, x1, lx_bf, tsum);

    // 6) hg = gelu(ln2 @ Wfc + bfc) bf16 + per-row sumsq -> tsum (fused; no hfc round-trip)
    k_gemm_gelu<<<dim3(32, 32, 1), blk, 0, stream>>>(
        lx_bf, WfcT, bfc, hg_bf, tsum);

    // 7) h2 = hg @ WpjT' + bpj + sqrt(tsum+1)*Wpj[0], split-K (2048+2048); XCD swizzle
    k_gemm_mfma<float><<<dim3(8, 32, 2), blk, 0, stream>>>(
        hg_bf, WpjT, bpj, 1023, h2a, h2b, 1024, 4096, 2048, 4096, 1, tsum, Wpj);

    // 8) out = lresnet(x1, lift(h2a+h2b), w2) (vectorized)
    k_lresnet<<<ROWS, blk, 0, stream>>>(x1, h2a, h2b, w2, out);
}

// Round 9
// 361.959 us; speedup vs baseline: 1.0885x; 1.0885x over previous
//
#include <hip/hip_runtime.h>
#include <math.h>

#define BB 4
#define NN 1024
#define DD 1024
#define HH 16
#define ROWS (BB*NN)   // 4096

typedef __attribute__((ext_vector_type(8))) short bf16x8;
typedef __attribute__((ext_vector_type(4))) float f32x4;
typedef __attribute__((ext_vector_type(4))) unsigned short u16x4;
typedef __attribute__((ext_vector_type(8))) unsigned short u16x8;
typedef unsigned short u16;

__device__ __forceinline__ u16 f2bf(float f) {
    union { float f; unsigned u; } v; v.f = f;
    unsigned r = v.u + 0x7fff + ((v.u >> 16) & 1);
    return (u16)(r >> 16);
}
__device__ __forceinline__ float bf2f(u16 u) {
    union { unsigned u; float f; } v; v.u = ((unsigned)u) << 16; return v.f;
}

// async global->LDS, 16B per lane. LDS dest = wave-uniform base (+lane*16 implicit).
__device__ __forceinline__ void async16(const void* g, void* l) {
    __builtin_amdgcn_global_load_lds(
        (__attribute__((address_space(1))) void*)(uintptr_t)g,
        (__attribute__((address_space(3))) void*)(uintptr_t)l,
        16, 0, 0);
}

// ---------------- block reduce (blockDim = 256) ----------------
__device__ __forceinline__ float block_reduce_sum(float v, float* sm) {
    #pragma unroll
    for (int o = 32; o > 0; o >>= 1) v += __shfl_down(v, o);
    int lane = threadIdx.x & 63, wid = threadIdx.x >> 6;
    if (lane == 0) sm[wid] = v;
    __syncthreads();
    if (wid == 0) {
        v = (lane < (int)(blockDim.x >> 6)) ? sm[lane] : 0.f;
        #pragma unroll
        for (int o = 2; o > 0; o >>= 1) v += __shfl_down(v, o);
        if (lane == 0) sm[0] = v;
    }
    __syncthreads();
    float r = sm[0];
    __syncthreads();
    return r;
}

// 3 sums in one barrier round
__device__ __forceinline__ void block_reduce3(float& a, float& b, float& c, float* sm) {
    #pragma unroll
    for (int o = 32; o > 0; o >>= 1) {
        a += __shfl_down(a, o); b += __shfl_down(b, o); c += __shfl_down(c, o);
    }
    int lane = threadIdx.x & 63, wid = threadIdx.x >> 6;
    if (lane == 0) { sm[wid] = a; sm[8 + wid] = b; sm[16 + wid] = c; }
    __syncthreads();
    int nw = (int)(blockDim.x >> 6);
    if (wid == 0) {
        float va = (lane < nw) ? sm[lane] : 0.f;
        float vb = (lane < nw) ? sm[8 + lane] : 0.f;
        float vc = (lane < nw) ? sm[16 + lane] : 0.f;
        #pragma unroll
        for (int o = 2; o > 0; o >>= 1) {
            va += __shfl_down(va, o); vb += __shfl_down(vb, o); vc += __shfl_down(vc, o);
        }
        if (lane == 0) { sm[0] = va; sm[8] = vb; sm[16] = vc; }
    }
    __syncthreads();
    a = sm[0]; b = sm[8]; c = sm[16];
    __syncthreads();
}

// ---------------- fused: weight transpose+convert (6 weights) AND layernorm1 ----------------
// 64x64 tiles: guarded scalar f32 loads (256B row segments), u16x4 stores (128B row
// segments) -- ~2x store efficiency vs the old 32x32 scalar-store version.
__global__ __launch_bounds__(256) void k_pre(
        const float* __restrict__ Wq_, const float* __restrict__ Wk_,
        const float* __restrict__ Wv_, const float* __restrict__ Wo_,
        const float* __restrict__ Wfc_, const float* __restrict__ Wpj_,
        u16* __restrict__ WqkvT, u16* __restrict__ WoT,
        u16* __restrict__ WfcT, u16* __restrict__ WpjT,
        const float* __restrict__ x, const float* __restrict__ g1,
        const float* __restrict__ be1, u16* __restrict__ lnout) {
    __shared__ float t[64][65];   // 16.6 KB
    int bid = blockIdx.x;
    int tid = threadIdx.x;
    if (bid < 3088) {
        const float* W; u16* out; int K, N, Kpad, Npad, gx;
        if (bid < 256)       { W = Wq_;  out = WqkvT;            K = 1024; N = 1024; Kpad = 1024; Npad = 1024; gx = 16; }
        else if (bid < 512)  { W = Wk_;  out = WqkvT + 1048576;  K = 1024; N = 1024; Kpad = 1024; Npad = 1024; gx = 16; bid -= 256; }
        else if (bid < 768)  { W = Wv_;  out = WqkvT + 2097152;  K = 1024; N = 1024; Kpad = 1024; Npad = 1024; gx = 16; bid -= 512; }
        else if (bid < 1040) { W = Wo_;  out = WoT;              K = 1040; N = 1023; Kpad = 1088; Npad = 1024; gx = 17; bid -= 768; }
        else if (bid < 2064) { W = Wfc_; out = WfcT;             K = 1024; N = 4095; Kpad = 1024; Npad = 4096; gx = 16; bid -= 1040; }
        else                 { W = Wpj_; out = WpjT;             K = 4096; N = 1023; Kpad = 4096; Npad = 1024; gx = 64; bid -= 2064; }
        int k0 = (bid % gx) * 64, n0 = (bid / gx) * 64;
        int tx = tid & 63, ty = tid >> 6;
        #pragma unroll
        for (int i = 0; i < 16; ++i) {
            int kk = i * 4 + ty;
            int k = k0 + kk, n = n0 + tx;
            t[kk][tx] = (k < K && n < N) ? W[(size_t)k * N + n] : 0.f;
        }
        __syncthreads();
        int cx = tid & 15, cy = tid >> 4;
        #pragma unroll
        for (int i = 0; i < 4; ++i) {
            int nn = cy + i * 16;
            int n = n0 + nn;
            if (n < Npad) {
                u16x4 v;
                #pragma unroll
                for (int e = 0; e < 4; ++e) v[e] = f2bf(t[cx * 4 + e][nn]);
                *(u16x4*)&out[(size_t)n * Kpad + k0 + cx * 4] = v;
            }
        }
    } else {
        float* sm = &t[0][0];
        int row = bid - 3088;
        const float4* xr4 = (const float4*)(x + (size_t)row * DD);
        float4 xv = xr4[tid];
        float s = 0.f, ss = 0.f, dummy = 0.f;
        #pragma unroll
        for (int e = 0; e < 4; ++e) {
            if (tid | e) {
                float v = ((const float*)&xv)[e];
                s += v; ss += v * v;
            }
        }
        block_reduce3(s, ss, dummy, sm);
        float mu = s * (1.f / 1023.f);
        float var = ss * (1.f / 1023.f) - mu * mu;
        float rstd = rsqrtf(var + 1e-5f);
        float vo[4]; float s2 = 0.f;
        #pragma unroll
        for (int e = 0; e < 4; ++e) {
            int c = 4 * tid + e;
            if (c > 0) {
                float v = (((const float*)&xv)[e] - mu) * rstd * g1[c - 1] + be1[c - 1];
                vo[e] = v; s2 += v * v;
            } else vo[e] = 0.f;
        }
        s2 = block_reduce_sum(s2, sm);
        u16x4 lo;
        #pragma unroll
        for (int e = 0; e < 4; ++e) lo[e] = f2bf(vo[e]);
        if (tid == 0) lo[0] = f2bf(sqrtf(s2 + 1.f));
        ((u16x4*)(lnout + (size_t)row * DD))[tid] = lo;
    }
}

// ---------------- bf16 MFMA GEMM: single-barrier double-buffered K-loop ----------------
// u16 output: LDS-staged epilogue with chunk-XOR swizzle (bank-conflict-free writes),
// coalesced u16x8 copy-out. float: direct stores.
__device__ __forceinline__ void cstore(float* p, float v) { *p = v; }
__device__ __forceinline__ void cstore(u16* p, float v) { *p = f2bf(v); }

template <typename OT>
__global__ __launch_bounds__(256) void k_gemm_mfma(
        const u16* __restrict__ A, const u16* __restrict__ BT,
        const float* __restrict__ bias, int nbias,
        OT* __restrict__ C0, OT* __restrict__ C1,
        int ldc, int ldab, int ksplit, int K, int swz) {
    __shared__ __align__(16) u16 smem[32768];   // As | Bs during K-loop; C-staging after
    int z = blockIdx.z;
    int kbeg = z ? ksplit : 0;
    int kend = z ? K : ksplit;
    OT* C = z ? C1 : C0;
    const float* bs = z ? nullptr : bias;

    int bx = blockIdx.x, by = blockIdx.y;
    if (swz) {
        // hw XCD = (bx + nx*by) % 8. Remap so XCD c owns m-panels [c*ny/8, ...).
        int nx = gridDim.x, ny = gridDim.y;
        int flat = bx + nx * by;
        int c = flat & 7, i = flat >> 3;
        int hi = i / nx;
        by = c * (ny >> 3) + hi;
        bx = i - hi * nx;
    }

    int tid = threadIdx.x;
    int wave = tid >> 6, lane = tid & 63;
    int quad = lane >> 4, m16 = lane & 15;
    int n0 = bx * 128, m0 = by * 128;
    int wm = (wave & 1) * 64, wn = (wave >> 1) * 64;

    f32x4 acc[4][4];
    #pragma unroll
    for (int t = 0; t < 4; ++t)
        #pragma unroll
        for (int u = 0; u < 4; ++u) acc[t][u] = (f32x4){0.f, 0.f, 0.f, 0.f};

    int r8 = lane >> 3;
    int cc = (lane & 7) ^ r8;               // XOR chunk swizzle (bank-conflict-free, measured 0)
    int srow = wave * 32 + r8;
    const u16* ag = A  + (size_t)(m0 + srow) * ldab + cc * 8;
    const u16* bg = BT + (size_t)(n0 + srow) * ldab + cc * 8;

    auto stage = [&](int k0, int s) {
        #pragma unroll
        for (int j = 0; j < 4; ++j) {
            async16(ag + (size_t)(j * 8) * ldab + k0, &smem[s * 8192 + (wave * 32 + j * 8) * 64]);
            async16(bg + (size_t)(j * 8) * ldab + k0, &smem[16384 + s * 8192 + (wave * 32 + j * 8) * 64]);
        }
    };

    int niter = (kend - kbeg) >> 6;
    stage(kbeg, 0);
    for (int it = 0; it < niter; ++it) {
        int cur = it & 1;
        __syncthreads();                    // drains stage(it) + prior iter's LDS reads
        if (it + 1 < niter) stage(kbeg + (it + 1) * 64, cur ^ 1);
        #pragma unroll
        for (int kk = 0; kk < 2; ++kk) {
            bf16x8 af[4], bfr[4];
            #pragma unroll
            for (int t = 0; t < 4; ++t) {
                int slot = (kk * 4 + quad) ^ (m16 & 7);
                af[t] = *(const bf16x8*)&smem[cur * 8192 + (wm + t * 16 + m16) * 64 + slot * 8];
            }
            #pragma unroll
            for (int u = 0; u < 4; ++u) {
                int slot = (kk * 4 + quad) ^ (m16 & 7);
                bfr[u] = *(const bf16x8*)&smem[16384 + cur * 8192 + (wn + u * 16 + m16) * 64 + slot * 8];
            }
            #pragma unroll
            for (int t = 0; t < 4; ++t)
                #pragma unroll
                for (int u = 0; u < 4; ++u)
                    acc[t][u] = __builtin_amdgcn_mfma_f32_16x16x32_bf16(af[t], bfr[u], acc[t][u], 0, 0, 0);
        }
    }
    if constexpr (sizeof(OT) == 2) {
        // bf16 out: stage 128x128 u16 tile in LDS (chunk-XOR swizzled writes:
        // rows written simultaneously by the 4 quads land in disjoint bank groups),
        // then coalesced row copies with the inverse chunk permutation.
        __syncthreads();
        #pragma unroll
        for (int u = 0; u < 4; ++u) {
            int col = n0 + wn + u * 16 + m16;
            int lcol = wn + u * 16 + m16;
            float bv = (bs != nullptr && col < nbias) ? bs[col] : 0.f;
            #pragma unroll
            for (int t = 0; t < 4; ++t) {
                #pragma unroll
                for (int r = 0; r < 4; ++r) {
                    int row = wm + t * 16 + quad * 4 + r;
                    int sc = (((lcol >> 3) ^ ((row >> 2) & 7)) << 3) + (lcol & 7);
                    smem[row * 128 + sc] = f2bf(acc[t][u][r] + bv);
                }
            }
        }
        __syncthreads();
        u16* Cg = (u16*)C;
        for (int i = tid; i < 2048; i += 256) {
            int rr = i >> 4, ch = i & 15;
            ((u16x8*)(Cg + (size_t)(m0 + rr) * ldc + n0))[ch] =
                ((const u16x8*)(smem + rr * 128))[ch ^ ((rr >> 2) & 7)];
        }
    } else {
        #pragma unroll
        for (int u = 0; u < 4; ++u) {
            int col = n0 + wn + u * 16 + m16;
            if (col < nbias) {
                float bv = (bs != nullptr) ? bs[col] : 0.f;
                #pragma unroll
                for (int t = 0; t < 4; ++t) {
                    #pragma unroll
                    for (int r = 0; r < 4; ++r) {
                        int row = m0 + wm + t * 16 + quad * 4 + r;
                        cstore(C + (size_t)row * ldc + col, acc[t][u][r] + bv);
                    }
                }
            }
        }
    }
}

// ---------------- fused QKV GEMM + bias + lift + head layouts (direct-store epilogue) ----------------
__global__ __launch_bounds__(256) void k_gemm_qkv(
        const u16* __restrict__ A, const u16* __restrict__ BT,
        const float* __restrict__ bq, const float* __restrict__ bk,
        const float* __restrict__ bv,
        u16* __restrict__ Qp, u16* __restrict__ Kp, u16* __restrict__ V2) {
    __shared__ __align__(16) u16 smem[32768];
    int tid = threadIdx.x;
    int wave = tid >> 6, lane = tid & 63;
    int quad = lane >> 4, m16 = lane & 15;
    int n0 = blockIdx.x * 128, m0 = blockIdx.y * 128;
    int wm = (wave & 1) * 64, wn = (wave >> 1) * 64;

    f32x4 acc[4][4];
    #pragma unroll
    for (int t = 0; t < 4; ++t)
        #pragma unroll
        for (int u = 0; u < 4; ++u) acc[t][u] = (f32x4){0.f, 0.f, 0.f, 0.f};

    int r8 = lane >> 3;
    int cc = (lane & 7) ^ r8;
    int srow = wave * 32 + r8;
    const u16* ag = A  + (size_t)(m0 + srow) * 1024 + cc * 8;
    const u16* bg = BT + (size_t)(n0 + srow) * 1024 + cc * 8;

    auto stage = [&](int k0, int s) {
        #pragma unroll
        for (int j = 0; j < 4; ++j) {
            async16(ag + (size_t)(j * 8) * 1024 + k0, &smem[s * 8192 + (wave * 32 + j * 8) * 64]);
            async16(bg + (size_t)(j * 8) * 1024 + k0, &smem[16384 + s * 8192 + (wave * 32 + j * 8) * 64]);
        }
    };

    stage(0, 0);
    for (int it = 0; it < 16; ++it) {
        int cur = it & 1;
        __syncthreads();
        if (it + 1 < 16) stage((it + 1) * 64, cur ^ 1);
        #pragma unroll
        for (int kk = 0; kk < 2; ++kk) {
            bf16x8 af[4], bfr[4];
            #pragma unroll
            for (int t = 0; t < 4; ++t) {
                int slot = (kk * 4 + quad) ^ (m16 & 7);
                af[t] = *(const bf16x8*)&smem[cur * 8192 + (wm + t * 16 + m16) * 64 + slot * 8];
            }
            #pragma unroll
            for (int u = 0; u < 4; ++u) {
                int slot = (kk * 4 + quad) ^ (m16 & 7);
                bfr[u] = *(const bf16x8*)&smem[16384 + cur * 8192 + (wn + u * 16 + m16) * 64 + slot * 8];
            }
            #pragma unroll
            for (int t = 0; t < 4; ++t)
                #pragma unroll
                for (int u = 0; u < 4; ++u)
                    acc[t][u] = __builtin_amdgcn_mfma_f32_16x16x32_bf16(af[t], bfr[u], acc[t][u], 0, 0, 0);
        }
    }

    // ---- epilogue: build heads in-place (direct stores; measured faster than LDS staging) ----
    int sec = n0 >> 10;                       // 0=Q 1=K 2=V (uniform per block)
    int h = ((n0 & 1023) + wn) >> 6;          // this wave's head
    int b = m0 >> 10;                         // batch (uniform per block)
    int b16h = b * 16 + h;
    const float* bias = (sec == 0) ? bq : (sec == 1) ? bk : bv;
    float bvu[4];
    #pragma unroll
    for (int u = 0; u < 4; ++u) bvu[u] = bias[h * 64 + u * 16 + m16];

    if (sec < 2) {
        const int strd = (sec == 0) ? 96 : 104;
        u16* P = (sec == 0) ? Qp : Kp;
        const float tsign = (sec == 0) ? -1.f : 1.f;
        #pragma unroll
        for (int t = 0; t < 4; ++t) {
            #pragma unroll
            for (int r = 0; r < 4; ++r) {
                int n = (m0 + wm + t * 16 + quad * 4 + r) & 1023;
                u16* drow = P + ((size_t)b16h * 1024 + n) * strd;
                float vv[4]; float ss = 0.f;
                #pragma unroll
                for (int u = 0; u < 4; ++u) { vv[u] = acc[t][u][r] + bvu[u]; ss += vv[u] * vv[u]; }
                ss += __shfl_xor(ss, 1); ss += __shfl_xor(ss, 2);
                ss += __shfl_xor(ss, 4); ss += __shfl_xor(ss, 8);
                #pragma unroll
                for (int u = 0; u < 4; ++u) drow[1 + u * 16 + m16] = f2bf(vv[u]);
                if (m16 == 0) drow[0] = f2bf(tsign * sqrtf(ss + 1.f));
                drow[65 + m16] = 0;
                if (m16 < 15) drow[81 + m16] = 0;
            }
        }
    } else {
        int tile = ((m0 & 1023) + wm) >> 6;   // this wave's 64-token tile
        size_t tbase = ((size_t)b16h * 16 + tile) * 6144;
        #pragma unroll
        for (int t = 0; t < 4; ++t) {
            int tok0 = t * 16 + quad * 4;
            u16x4 tc;
            u16x4 pk[4];
            #pragma unroll
            for (int r = 0; r < 4; ++r) {
                float vv[4]; float ss = 0.f;
                #pragma unroll
                for (int u = 0; u < 4; ++u) { vv[u] = acc[t][u][r] + bvu[u]; ss += vv[u] * vv[u]; }
                ss += __shfl_xor(ss, 1); ss += __shfl_xor(ss, 2);
                ss += __shfl_xor(ss, 4); ss += __shfl_xor(ss, 8);
                tc[r] = f2bf(sqrtf(ss + 1.f));
                #pragma unroll
                for (int u = 0; u < 4; ++u) pk[u][r] = f2bf(vv[u]);
            }
            #pragma unroll
            for (int u = 0; u < 4; ++u) {
                int d = u * 16 + m16;
                *(u16x4*)&V2[tbase + (size_t)(1 + d) * 72 + tok0] = pk[u];
            }
            if (m16 == 0) *(u16x4*)&V2[tbase + tok0] = tc;   // time row (d=0)
        }
        // zero pad rows d=65..79 (read by PV MFMA, must be 0)
        for (int i = lane; i < 240; i += 64) {
            int rr = 65 + (i >> 4), sg = (i & 15) << 2;
            *(u16x4*)&V2[tbase + (size_t)rr * 72 + sg] = (u16x4){0, 0, 0, 0};
        }
    }
}

// ---------------- MFMA flash attention v5: 8-wave blocks for 2x occupancy ----------------
#define AKS 104
#define AVS 72
#define APS 88
#define KTILE_U16 (64 * AKS)   // 6656
#define VTILE_U16 6144
#define EXPC 0.36067376f       // 0.25 * log2(e)
__global__ __launch_bounds__(512) void k_attn_mfma(
        const u16* __restrict__ Qp, const u16* __restrict__ Kp,
        const u16* __restrict__ V2, u16* __restrict__ cat) {
    __shared__ __align__(16) u16 Klds[2][KTILE_U16];
    __shared__ __align__(16) u16 Vlds[2][VTILE_U16];
    __shared__ __align__(16) u16 Plds[8][16 * APS];
    int tid = threadIdx.x;
    int wave = tid >> 6, lane = tid & 63;
    int quad = lane >> 4, m = lane & 15;
    int wq = wave & 3, g = wave >> 2;
    int bid = blockIdx.x;
    int bh = ((bid & 7) << 3) | (bid >> 6);
    int qt = (bid >> 3) & 7;

    const u16* kg = Kp + (size_t)bh * 16 * KTILE_U16;
    const u16* vg = V2 + (size_t)bh * 16 * VTILE_U16;

    bf16x8 aq[3];
    {
        const u16* qptr = Qp + ((size_t)bh * 1024 + qt * 128 + g * 64 + wq * 16 + m) * 96;
        aq[0] = *(const bf16x8*)(qptr + quad * 8);
        aq[1] = *(const bf16x8*)(qptr + 32 + quad * 8);
        aq[2] = *(const bf16x8*)(qptr + 64 + quad * 8);
    }

    f32x4 O[5];
    #pragma unroll
    for (int i = 0; i < 5; ++i) O[i] = (f32x4){0.f, 0.f, 0.f, 0.f};

    auto stage = [&](int kt, int s) {
        const u16* kt_p = kg + kt * KTILE_U16 + lane * 8;
        const u16* vt_p = vg + kt * VTILE_U16 + lane * 8;
        for (int i = wave; i < 25; i += 8) {
            if (i < 13) async16(kt_p + i * 512, &Klds[s][i * 512]);
            else        async16(vt_p + (i - 13) * 512, &Vlds[s][(i - 13) * 512]);
        }
    };

    stage(0, 0);
    for (int kt = 0; kt < 16; ++kt) {
        int cur = kt & 1;
        __syncthreads();
        if (kt < 15) stage(kt + 1, cur ^ 1);
        u16* pw = &Plds[wave][0];
        #pragma unroll
        for (int nt = 0; nt < 4; ++nt) {
            f32x4 acc = (f32x4){0.f, 0.f, 0.f, 0.f};
            const u16* kr = &Klds[cur][(nt * 16 + m) * AKS + quad * 8];
            acc = __builtin_amdgcn_mfma_f32_16x16x32_bf16(*(const bf16x8*)(kr),      aq[0], acc, 0, 0, 0);
            acc = __builtin_amdgcn_mfma_f32_16x16x32_bf16(*(const bf16x8*)(kr + 32), aq[1], acc, 0, 0, 0);
            acc = __builtin_amdgcn_mfma_f32_16x16x32_bf16(*(const bf16x8*)(kr + 64), aq[2], acc, 0, 0, 0);
            unsigned pk0, pk1;
            {
                union { float f; unsigned u; } a0, a1, a2, a3;
                a0.f = __builtin_amdgcn_exp2f(fmaf(acc[0], EXPC, EXPC));
                a1.f = __builtin_amdgcn_exp2f(fmaf(acc[1], EXPC, EXPC));
                a2.f = __builtin_amdgcn_exp2f(fmaf(acc[2], EXPC, EXPC));
                a3.f = __builtin_amdgcn_exp2f(fmaf(acc[3], EXPC, EXPC));
                pk0 = ((a0.u + 0x8000u) >> 16) | (((a1.u + 0x8000u) >> 16) << 16);
                pk1 = ((a2.u + 0x8000u) >> 16) | (((a3.u + 0x8000u) >> 16) << 16);
            }
            uint2 pk; pk.x = pk0; pk.y = pk1;
            *(uint2*)&pw[m * APS + nt * 16 + quad * 4] = pk;
        }
        #pragma unroll
        for (int kc = 0; kc < 2; ++kc) {
            bf16x8 ap = *(const bf16x8*)&Plds[wave][m * APS + kc * 32 + quad * 8];
            #pragma unroll
            for (int vt = 0; vt < 5; ++vt) {
                bf16x8 bv = *(const bf16x8*)&Vlds[cur][(vt * 16 + m) * AVS + kc * 32 + quad * 8];
                O[vt] = __builtin_amdgcn_mfma_f32_16x16x32_bf16(ap, bv, O[vt], 0, 0, 0);
            }
        }
    }
    int b = bh >> 4, h = bh & 15;
    #pragma unroll
    for (int r = 0; r < 4; ++r) {
        float part = 0.f;
        #pragma unroll
        for (int vt = 0; vt < 5; ++vt) {
            int c = vt * 16 + m;
            float o = O[vt][r];
            part += (c == 0) ? o * o : -o * o;
        }
        part += __shfl_xor(part, 1);
        part += __shfl_xor(part, 2);
        part += __shfl_xor(part, 4);
        part += __shfl_xor(part, 8);
        float rden = rsqrtf(fmaxf(part, 1e-8f));
        int n = qt * 128 + g * 64 + wq * 16 + quad * 4 + r;
        u16* crow = cat + (size_t)(b * 1024 + n) * 1088 + h * 65;
        #pragma unroll
        for (int vt = 0; vt < 5; ++vt) {
            int c = vt * 16 + m;
            if (c < 65) crow[c] = f2bf(O[vt][r] * rden);
        }
    }
    if (h == 15) {
        for (int i = tid; i < 128 * 48; i += 512) {
            int rr = i / 48, c = i - rr * 48;
            int n = qt * 128 + rr;
            cat[(size_t)(b * 1024 + n) * 1088 + 1040 + c] = 0;
        }
    }
}

// ---------------- fused lift(y0+y1) + lresnet + layernorm2 (vectorized, aligned) ----------------
__global__ __launch_bounds__(256) void k_lresnet_ln(
        const float* __restrict__ x, const float* __restrict__ y0,
        const float* __restrict__ y1, const float* __restrict__ wscale,
        const float* __restrict__ g2, const float* __restrict__ be2,
        float* __restrict__ x1, u16* __restrict__ lnout) {
    __shared__ float sm[24];
    __shared__ float edge[256];
    int row = blockIdx.x, tid = threadIdx.x;
    float w = *wscale;
    float4 xv = ((const float4*)(x  + (size_t)row * DD))[tid];
    float4 av = ((const float4*)(y0 + (size_t)row * 1024))[tid];
    float4 bv = ((const float4*)(y1 + (size_t)row * 1024))[tid];
    float yv[4];
    #pragma unroll
    for (int e = 0; e < 4; ++e) yv[e] = ((const float*)&av)[e] + ((const float*)&bv)[e];
    edge[tid] = yv[3];
    float sy = 0.f;
    #pragma unroll
    for (int e = 0; e < 4; ++e) if (4 * tid + e < 1023) sy += yv[e] * yv[e];
    __syncthreads();
    float yprev = tid ? edge[tid - 1] : 0.f;
    float zv[4];
    float sz = 0.f, szs = 0.f;
    #pragma unroll
    for (int e = 0; e < 4; ++e) {
        float yc = (e == 0) ? yprev : yv[e - 1];   // y[c-1] for col c=4tid+e
        float z = ((const float*)&xv)[e] + w * yc;
        zv[e] = z;
        if (tid | e) { sz += z * z; szs += z; }
    }
    block_reduce3(sy, sz, szs, sm);
    float x0 = x[(size_t)row * DD];
    float z0 = x0 + w * sqrtf(sy + 1.f);
    float q = z0 * z0 - sz;
    float rden = rsqrtf(fmaxf(q, 1e-8f));
    float mu = rden * szs * (1.f / 1023.f);
    float ex2 = rden * rden * sz * (1.f / 1023.f);
    float rstd = rsqrtf(ex2 - mu * mu + 1e-5f);
    float4 xo; float vo[4]; float s2 = 0.f;
    #pragma unroll
    for (int e = 0; e < 4; ++e) {
        int c = 4 * tid + e;
        float xn = zv[e] * rden;
        ((float*)&xo)[e] = xn;
        if (c > 0) {
            float v = (xn - mu) * rstd * g2[c - 1] + be2[c - 1];
            vo[e] = v; s2 += v * v;
        } else vo[e] = 0.f;
    }
    if (tid == 0) ((float*)&xo)[0] = z0 * rden;
    ((float4*)(x1 + (size_t)row * DD))[tid] = xo;
    s2 = block_reduce_sum(s2, sm);
    u16x4 lo;
    #pragma unroll
    for (int e = 0; e < 4; ++e) lo[e] = f2bf(vo[e]);
    if (tid == 0) lo[0] = f2bf(sqrtf(s2 + 1.f));
    ((u16x4*)(lnout + (size_t)row * DD))[tid] = lo;
}

// ---------------- final lresnet (fp32 out, vectorized, aligned) ----------------
__global__ __launch_bounds__(256) void k_lresnet(
        const float* __restrict__ x, const float* __restrict__ y0,
        const float* __restrict__ y1, const float* __restrict__ wscale,
        float* __restrict__ out) {
    __shared__ float sm[24];
    __shared__ float edge[256];
    int row = blockIdx.x, tid = threadIdx.x;
    float w = *wscale;
    float4 xv = ((const float4*)(x  + (size_t)row * DD))[tid];
    float4 av = ((const float4*)(y0 + (size_t)row * 1024))[tid];
    float4 bv = ((const float4*)(y1 + (size_t)row * 1024))[tid];
    float yv[4];
    #pragma unroll
    for (int e = 0; e < 4; ++e) yv[e] = ((const float*)&av)[e] + ((const float*)&bv)[e];
    edge[tid] = yv[3];
    float sy = 0.f;
    #pragma unroll
    for (int e = 0; e < 4; ++e) if (4 * tid + e < 1023) sy += yv[e] * yv[e];
    __syncthreads();
    float yprev = tid ? edge[tid - 1] : 0.f;
    float zv[4];
    float sz = 0.f, dummy = 0.f;
    #pragma unroll
    for (int e = 0; e < 4; ++e) {
        float yc = (e == 0) ? yprev : yv[e - 1];
        float z = ((const float*)&xv)[e] + w * yc;
        zv[e] = z;
        if (tid | e) sz += z * z;
    }
    block_reduce3(sy, sz, dummy, sm);
    float x0 = x[(size_t)row * DD];
    float z0 = x0 + w * sqrtf(sy + 1.f);
    float q = z0 * z0 - sz;
    float rden = rsqrtf(fmaxf(q, 1e-8f));
    float4 o;
    #pragma unroll
    for (int e = 0; e < 4; ++e) ((float*)&o)[e] = zv[e] * rden;
    if (tid == 0) ((float*)&o)[0] = z0 * rden;
    ((float4*)(out + (size_t)row * DD))[tid] = o;
}

// ---------------- gelu (exact) + lift: UNSHIFTED bf16 in -> lifted bf16 out ----------------
__global__ __launch_bounds__(256) void k_gelu_lift(
        const u16* __restrict__ hfc, u16* __restrict__ hg) {
    __shared__ float sm[8];
    __shared__ u16 edge[512];
    int row = blockIdx.x, tid = threadIdx.x;
    const u16* hr = hfc + (size_t)row * 4096;
    u16* gr = hg + (size_t)row * 4096;
    u16x8 hv0 = *(const u16x8*)(hr + tid * 8);
    u16x8 hv1 = *(const u16x8*)(hr + 2048 + tid * 8);
    edge[tid] = hv0[7];
    edge[256 + tid] = hv1[7];
    __syncthreads();
    u16 p0 = tid ? edge[tid - 1] : (u16)0;
    u16 p1 = edge[255 + tid];
    float s2 = 0.f;
    u16x8 ov0, ov1;
    #pragma unroll
    for (int e = 0; e < 8; ++e) {
        int c = 8 * tid + e;
        float gl = 0.f;
        if (c > 0) {
            float v = bf2f((e == 0) ? p0 : hv0[e - 1]);
            gl = 0.5f * v * (1.f + erff(v * 0.70710678f));
            s2 += gl * gl;
        }
        ov0[e] = f2bf(gl);
    }
    #pragma unroll
    for (int e = 0; e < 8; ++e) {
        float v = bf2f((e == 0) ? p1 : hv1[e - 1]);
        float gl = 0.5f * v * (1.f + erff(v * 0.70710678f));
        s2 += gl * gl;
        ov1[e] = f2bf(gl);
    }
    *(u16x8*)(gr + tid * 8) = ov0;
    *(u16x8*)(gr + 2048 + tid * 8) = ov1;
    s2 = block_reduce_sum(s2, sm);
    if (tid == 0) gr[0] = f2bf(sqrtf(s2 + 1.f));
}

// ---------------- launch ----------------
extern "C" void kernel_launch(void* const* d_in, const int* in_sizes, int n_in,
                              void* d_out, int out_size, void* d_ws, size_t ws_size,
                              hipStream_t stream) {
    const float* x   = (const float*)d_in[0];
    const float* g1  = (const float*)d_in[1];
    const float* b1  = (const float*)d_in[2];
    const float* Wq  = (const float*)d_in[3];
    const float* bq  = (const float*)d_in[4];
    const float* Wk  = (const float*)d_in[5];
    const float* bk  = (const float*)d_in[6];
    const float* Wv  = (const float*)d_in[7];
    const float* bv  = (const float*)d_in[8];
    const float* Wo  = (const float*)d_in[9];
    const float* bo  = (const float*)d_in[10];
    const float* g2  = (const float*)d_in[11];
    const float* b2  = (const float*)d_in[12];
    const float* Wfc = (const float*)d_in[13];
    const float* bfc = (const float*)d_in[14];
    const float* Wpj = (const float*)d_in[15];
    const float* bpj = (const float*)d_in[16];
    const float* w1  = (const float*)d_in[17];
    const float* w2  = (const float*)d_in[18];
    float* out = (float*)d_out;

    char* W = (char*)d_ws;
    // byte offsets; peak 117,571,584 B (unchanged)
    u16* lx_bf  = (u16*)(W + 0);            // 8 MB (ln1, later ln2)
    u16* WqkvT  = (u16*)(W + 8388608);      // [3072][1024]
    u16* WoT    = (u16*)(W + 14680064);     // [1024][1088]
    u16* WfcT   = (u16*)(W + 16908288);     // [4096][1024]
    u16* WpjT   = (u16*)(W + 25296896);     // [1024][4096]
    u16* Qp     = (u16*)(W + 58851328);     // 64x1024x96
    u16* Kp     = (u16*)(W + 71434240);     // 64x1024x104
    u16* V2     = (u16*)(W + 85065728);     // 64x16x6144
    u16* cat_bf = (u16*)(W + 97648640);     // 4096x1088
    float* ax0  = (float*)(W + 33685504);   // overlay (dead region); unshifted rows
    float* ax1  = (float*)(W + 50462720);   // overlay (dead region); unshifted rows
    float* x1   = (float*)(W + 67239936);   // overlay Qp-tail/Kp (dead)
    u16* hfc_bf = (u16*)(W + 84017152);     // 32MB, overlay Kp-tail/V2/cat (dead); unshifted
    u16* hg_bf  = (u16*)(W + 33685504);     // 32MB, overlay ax0/ax1 (dead); time-at-0
    float* h2a  = (float*)(W + 84017152);   // overlay hfc (dead after gelu); unshifted
    float* h2b  = (float*)(W + 100794368);

    dim3 blk(256);

    // 1) weight conversion (64x64 tiles, vectorized stores) + layernorm1 (fused)
    k_pre<<<7184, blk, 0, stream>>>(Wq, Wk, Wv, Wo, Wfc, Wpj,
                                    WqkvT, WoT, WfcT, WpjT,
                                    x, g1, b1, lx_bf);

    // 2) fused QKV GEMM + bias + lift + head layouts (direct-store epilogue)
    k_gemm_qkv<<<dim3(24, 32, 1), blk, 0, stream>>>(
        lx_bf, WqkvT, bq, bk, bv, Qp, Kp, V2);

    // 3) MFMA flash attention v5 (8-wave blocks, XCD-swizzled 1D grid)
    k_attn_mfma<<<512, dim3(512), 0, stream>>>(Qp, Kp, V2, cat_bf);

    // 4) ax = cat @ Wo + bo, split-K (576+512); XCD m-panel swizzle
    k_gemm_mfma<float><<<dim3(8, 32, 2), blk, 0, stream>>>(
        cat_bf, WoT, bo, 1023, ax0, ax1, 1024, 1088, 576, 1088, 1);

    // 5) x1 = lresnet(x, lift(ax0+ax1), w1); ln2 -> lx_bf (fused, vectorized)
    k_lresnet_ln<<<ROWS, blk, 0, stream>>>(x, ax0, ax1, w1, g2, b2, x1, lx_bf);

    // 6) hfc = ln2 @ Wfc + bfc (bf16 out, swizzled LDS-staged coalesced epilogue)
    k_gemm_mfma<u16><<<dim3(32, 32, 1), blk, 0, stream>>>(
        lx_bf, WfcT, bfc, 4095, hfc_bf, hfc_bf, 4096, 1024, 1024, 1024, 0);

    // 7) hg = lift(gelu(hfc)) bf16 (vectorized, edge-exchange)
    k_gelu_lift<<<ROWS, blk, 0, stream>>>(hfc_bf, hg_bf);

    // 8) h2 = hg @ Wpj + bpj, split-K (2048+2048); XCD m-panel swizzle
    k_gemm_mfma<float><<<dim3(8, 32, 2), blk, 0, stream>>>(
        hg_bf, WpjT, bpj, 1023, h2a, h2b, 1024, 4096, 2048, 4096, 1);

    // 9) out = lresnet(x1, lift(h2a+h2b), w2) (vectorized)
    k_lresnet<<<ROWS, blk, 0, stream>>>(x1, h2a, h2b, w2, out);
}